// Round 1
// baseline (154.459 us; speedup 1.0000x reference)
//
#include <hip/hip_runtime.h>

#define TPB 256

__device__ __forceinline__ float fast_rcp(float x) { return __builtin_amdgcn_rcpf(x); }
__device__ __forceinline__ float sigm(float x) { return fast_rcp(1.0f + __expf(-x)); }
__device__ __forceinline__ float ftanh(float x) { return 1.0f - 2.0f * fast_rcp(__expf(2.0f * x) + 1.0f); }

// PyTorch GRUCell, input=2, hidden=2. wih/whh are [6,2] row-major, b* are [6].
__device__ __forceinline__ void gru_cell(const float* wih, const float* whh,
                                         const float* bih, const float* bhh,
                                         float x0, float x1, float& h0, float& h1) {
  float gi[6], gh[6];
#pragma unroll
  for (int g = 0; g < 6; ++g) {
    gi[g] = fmaf(wih[2 * g], x0, fmaf(wih[2 * g + 1], x1, bih[g]));
    gh[g] = fmaf(whh[2 * g], h0, fmaf(whh[2 * g + 1], h1, bhh[g]));
  }
  float r0 = sigm(gi[0] + gh[0]);
  float r1 = sigm(gi[1] + gh[1]);
  float z0 = sigm(gi[2] + gh[2]);
  float z1 = sigm(gi[3] + gh[3]);
  float n0 = ftanh(fmaf(r0, gh[4], gi[4]));
  float n1 = ftanh(fmaf(r1, gh[5], gi[5]));
  h0 = fmaf(z0, h0 - n0, n0);
  h1 = fmaf(z1, h1 - n1, n1);
}

__global__ __launch_bounds__(TPB) void rec_policy_kernel(
    const float* __restrict__ x,
    const float* __restrict__ up_wih, const float* __restrict__ up_whh,
    const float* __restrict__ up_bih, const float* __restrict__ up_bhh,
    const float* __restrict__ down_wih, const float* __restrict__ down_whh,
    const float* __restrict__ down_bih, const float* __restrict__ down_bhh,
    const float* __restrict__ obs_w, const float* __restrict__ obs_b,
    const float* __restrict__ out_w, const float* __restrict__ out_b,
    float* __restrict__ out, int B) {
  __shared__ float sx[TPB * 19];   // input staging  (19456 B, block base 16B aligned)
  __shared__ float sout[TPB * 7];  // output staging (7168 B)
  __shared__ float sw[91];         // all weights/biases flattened

  const int tid = threadIdx.x;
  const int base = blockIdx.x * TPB;
  const int rows = min(TPB, B - base);

  // ---- stage weights (one-time, 91 scalars) ----
  if (tid < 91) {
    int i = tid;
    float v;
    if      (i < 12) v = up_wih[i];
    else if (i < 24) v = up_whh[i - 12];
    else if (i < 30) v = up_bih[i - 24];
    else if (i < 36) v = up_bhh[i - 30];
    else if (i < 48) v = down_wih[i - 36];
    else if (i < 60) v = down_whh[i - 48];
    else if (i < 66) v = down_bih[i - 60];
    else if (i < 72) v = down_bhh[i - 66];
    else if (i < 86) v = obs_w[i - 72];   // [2,7] row-major at 72..85
    else if (i < 88) v = obs_b[i - 86];
    else if (i < 90) v = out_w[i - 88];
    else             v = out_b[0];
    sw[i] = v;
  }

  // ---- stage x: coalesced float4 (full blocks) ----
  if (rows == TPB) {
    const float4* src = (const float4*)(x + (size_t)base * 19);
    float4* dst = (float4*)sx;
    for (int i = tid; i < TPB * 19 / 4; i += TPB) dst[i] = src[i];
  } else {
    for (int i = tid; i < rows * 19; i += TPB) sx[i] = x[(size_t)base * 19 + i];
  }
  __syncthreads();

  if (tid < rows) {
    const float* xr = sx + tid * 19;  // stride 19 (odd) -> <=2-way bank alias, free
    float hu[14];                      // h_up history for the down pass

    // ---- up GRU, 7 steps ----
    {
      float w[12], u[12], bi[6], bh[6];
#pragma unroll
      for (int i = 0; i < 12; ++i) { w[i] = sw[i]; u[i] = sw[12 + i]; }
#pragma unroll
      for (int i = 0; i < 6; ++i) { bi[i] = sw[24 + i]; bh[i] = sw[30 + i]; }
      float h0 = 0.f, h1 = 0.f;
#pragma unroll
      for (int t = 0; t < 7; ++t) {
        gru_cell(w, u, bi, bh, xr[5 + t], xr[12 + t], h0, h1);
        hu[2 * t] = h0;
        hu[2 * t + 1] = h1;
      }
    }

    // ---- obs linear: h = [obs(5) || h_last(2)] @ obs_w.T + obs_b ----
    float h0, h1;
    {
      float acc0 = sw[86], acc1 = sw[87];
#pragma unroll
      for (int k = 0; k < 5; ++k) {
        float c = xr[k];
        acc0 = fmaf(c, sw[72 + k], acc0);
        acc1 = fmaf(c, sw[79 + k], acc1);
      }
      acc0 = fmaf(hu[12], sw[77], fmaf(hu[13], sw[78], acc0));
      acc1 = fmaf(hu[12], sw[84], fmaf(hu[13], sw[85], acc1));
      h0 = acc0;
      h1 = acc1;
    }

    // ---- down GRU, 7 steps + per-step output ----
    {
      float w[12], u[12], bi[6], bh[6];
#pragma unroll
      for (int i = 0; i < 12; ++i) { w[i] = sw[36 + i]; u[i] = sw[48 + i]; }
#pragma unroll
      for (int i = 0; i < 6; ++i) { bi[i] = sw[60 + i]; bh[i] = sw[66 + i]; }
      float ow0 = sw[88], ow1 = sw[89], ob = sw[90];
#pragma unroll
      for (int t = 0; t < 7; ++t) {
        gru_cell(w, u, bi, bh, hu[2 * t], hu[2 * t + 1], h0, h1);
        sout[tid * 7 + t] = fmaf(ow0, h0, fmaf(ow1, h1, ob));
      }
    }
  }
  __syncthreads();

  // ---- coalesced float4 store ----
  if (rows == TPB) {
    float4* dst = (float4*)(out + (size_t)base * 7);
    const float4* src = (const float4*)sout;
    for (int i = tid; i < TPB * 7 / 4; i += TPB) dst[i] = src[i];
  } else {
    for (int i = tid; i < rows * 7; i += TPB) out[(size_t)base * 7 + i] = sout[i];
  }
}

extern "C" void kernel_launch(void* const* d_in, const int* in_sizes, int n_in,
                              void* d_out, int out_size, void* d_ws, size_t ws_size,
                              hipStream_t stream) {
  const float* x        = (const float*)d_in[0];
  const float* up_wih   = (const float*)d_in[1];
  const float* up_whh   = (const float*)d_in[2];
  const float* up_bih   = (const float*)d_in[3];
  const float* up_bhh   = (const float*)d_in[4];
  const float* down_wih = (const float*)d_in[5];
  const float* down_whh = (const float*)d_in[6];
  const float* down_bih = (const float*)d_in[7];
  const float* down_bhh = (const float*)d_in[8];
  const float* obs_w    = (const float*)d_in[9];
  const float* obs_b    = (const float*)d_in[10];
  const float* out_w    = (const float*)d_in[11];
  const float* out_b    = (const float*)d_in[12];
  float* out = (float*)d_out;

  const int B = in_sizes[0] / 19;
  const int blocks = (B + TPB - 1) / TPB;
  rec_policy_kernel<<<blocks, TPB, 0, stream>>>(
      x, up_wih, up_whh, up_bih, up_bhh, down_wih, down_whh, down_bih, down_bhh,
      obs_w, obs_b, out_w, out_b, out, B);
}